// Round 16
// baseline (192.932 us; speedup 1.0000x reference)
//
#include <hip/hip_runtime.h>

typedef _Float16 v8h __attribute__((ext_vector_type(8)));
typedef float    v4f __attribute__((ext_vector_type(4)));

#define MFMA16(a, b, c) __builtin_amdgcn_mfma_f32_16x16x32_f16((a), (b), (c), 0, 0, 0)

#define GLL16(gptr, lptr)                                                        \
  __builtin_amdgcn_global_load_lds((const __attribute__((address_space(1))) void*)(gptr), \
                                   (__attribute__((address_space(3))) void*)(lptr), 16, 0, 0)

// Block-diagonal Wbig (480x480) as 32(k)x16(n) MFMA fragments, built in-kernel.
// Fragment convention (A and B slots identical): lane l, elem e holds
// k = kt*32 + (l>>4)*8 + e; other dim = l&15.
// SWAPPED use: W-frag in A slot, x-frag in B slot -> lane l, reg j =
// out[row l&15][col ot*16 + (l>>4)*4 + j] -> one float4 store per ot.
__device__ __forceinline__ v8h build_frag(const float* __restrict__ W0,
                                          const float* __restrict__ W1,
                                          const float* __restrict__ W2,
                                          int ot, int kt, int lane) {
  const int n  = ot * 16 + (lane & 15);
  const int kb = kt * 32 + (lane >> 4) * 8;
  v8h v;
#pragma unroll
  for (int e = 0; e < 8; ++e) {
    const int k = kb + e;
    float wv = 0.0f;
    if (k < 128) {
      if (n < 128) wv = W0[k * 128 + n] * 0.08838834764831845f;           // 1/sqrt(128)
    } else if (k < 320) {
      if (n >= 128 && n < 320) {
        const int i = k - 128, o = n - 128;
        if (i % 3 == o % 3) wv = W1[(i / 3) * 64 + (o / 3)] * 0.125f;     // 1/sqrt(64)
      }
    } else {
      if (n >= 320) {
        const int i = k - 320, o = n - 320;
        if (i % 5 == o % 5) wv = W2[(i / 5) * 32 + (o / 5)] * 0.17677669529663687f; // 1/sqrt(32)
      }
    }
    v[e] = (_Float16)wv;
  }
  return v;
}

// Persistent 512-thread blocks, 1/CU. 16-row tiles (30720B) in a 5-slot LDS
// ring (153600B), staged THREE ahead via global_load_lds (source-side bank
// swizzle), grid-stride tile assignment, col-block wave partition, one
// barrier per tile:  iter c: stage(c+3) -> vmcnt(N) -> s_barrier -> compute(c)
// Ring safety: in window c, compute reads slot c%5 while gll writes land in
// slots (c+1..c+3)%5 (distances 1..3 mod 5); slot c%5 is rewritten only in
// window c+2 (two barriers later).
// vmcnt (issue order ...gll(c),S(c-3),gll(c+1),S(c-2),gll(c+2),S(c-1),gll(c+3)):
// steady N = 3G+3S retires exactly gll(c); peels 3G / 3G+S / 3G+2S;
// tail 2G+3S / G+3S / 3S. Frag-build loads sit between gll(2) and gll(3) in
// the queue -> every peel N is still <= true younger-count (safe).
// Partition: V=0 (w0,1) cb0 kts0-3 ots{w+2i,i<4}; V=1 (w2..5) cb1 kts4-9
// ots{6+w+4i,i<3}; V=2 (w6,7) cb2 kts10-14 ots{14+w+2i,i<5}.
template <int V, int G>
__device__ __forceinline__ void wave_main(const float* __restrict__ x,
                                          const float* __restrict__ W0,
                                          const float* __restrict__ W1,
                                          const float* __restrict__ W2,
                                          float* __restrict__ out,
                                          unsigned char* sm, int t, int b, int nc) {
  const int lane = t & 63;
  const int w    = t >> 6;
  const int r16  = lane & 15;
  const int g    = lane >> 4;

  constexpr int S  = (V == 0) ? 4 : (V == 1) ? 3 : 5;    // stores per tile
  constexpr int NF = (V == 0) ? 16 : (V == 1) ? 18 : 25; // resident frags

  // ---- staging: 16 rows x 1920B = 1920 granules; G gll per wave ----
  auto stage = [&](int tt, int slot) {
    const unsigned char* xt = (const unsigned char*)x + (size_t)tt * 30720u;
    unsigned char* buf = sm + (size_t)slot * 30720u;
#pragma unroll
    for (int i = 0; i < 4; ++i) {
      if (i < 3 || w < 6) {                    // wave-uniform; waves 0..5 do i=3
        const unsigned gl = (unsigned)(i * 512 + t);
        const unsigned r  = gl / 120u;
        const unsigned j  = gl - r * 120u;
        GLL16(xt + r * 1920u + ((j ^ (r & 7u)) << 4), buf + i * 8192 + w * 1024);
      }
    }
  };

  // ---- start the HBM stream first, build frags under it ----
  stage(b, 0);
  stage(b + 256, 1);
  stage(b + 2 * 256, 2);

  v8h f[NF];
  if constexpr (V == 0) {
#pragma unroll
    for (int i = 0; i < 4; ++i)
#pragma unroll
      for (int k = 0; k < 4; ++k)
        f[i * 4 + k] = build_frag(W0, W1, W2, w + 2 * i, k, lane);
  } else if constexpr (V == 1) {
#pragma unroll
    for (int i = 0; i < 3; ++i)
#pragma unroll
      for (int k = 0; k < 6; ++k)
        f[i * 6 + k] = build_frag(W0, W1, W2, 6 + w + 4 * i, 4 + k, lane);
  } else {
#pragma unroll
    for (int i = 0; i < 5; ++i)
#pragma unroll
      for (int k = 0; k < 5; ++k)
        f[i * 5 + k] = build_frag(W0, W1, W2, 14 + w + 2 * i, 10 + k, lane);
  }

#define LDAF(kt, dst)                                                                       \
  {                                                                                         \
    const unsigned j0 = (unsigned)((kt) * 8 + g * 2);                                       \
    const float4 lo = *reinterpret_cast<const float4*>(smc + rb + (((j0) ^ q) << 4));       \
    const float4 hi = *reinterpret_cast<const float4*>(smc + rb + ((((j0) + 1) ^ q) << 4)); \
    v8h v_;                                                                                 \
    v_[0] = (_Float16)lo.x; v_[1] = (_Float16)lo.y;                                         \
    v_[2] = (_Float16)lo.z; v_[3] = (_Float16)lo.w;                                         \
    v_[4] = (_Float16)hi.x; v_[5] = (_Float16)hi.y;                                         \
    v_[6] = (_Float16)hi.z; v_[7] = (_Float16)hi.w;                                         \
    dst = v_;                                                                               \
  }

  auto compute = [&](int tt, int slot) {
    const unsigned char* smc = sm + (size_t)slot * 30720u;
    const unsigned rb = (unsigned)r16 * 1920u;
    const unsigned q  = (unsigned)(r16 & 7u);
    float* const ob = out + ((size_t)tt * 16 + r16) * 480 + g * 4;
    if constexpr (V == 0) {
      v8h xr[4];
#pragma unroll
      for (int k = 0; k < 4; ++k) LDAF(k, xr[k]);
#pragma unroll
      for (int i = 0; i < 4; ++i) {
        v4f a = {0.f, 0.f, 0.f, 0.f};
#pragma unroll
        for (int k = 0; k < 4; ++k) a = MFMA16(f[i * 4 + k], xr[k], a);
        *reinterpret_cast<v4f*>(ob + (w + 2 * i) * 16) = a;
      }
    } else if constexpr (V == 1) {
      v8h xr[6];
#pragma unroll
      for (int k = 0; k < 6; ++k) LDAF(4 + k, xr[k]);
#pragma unroll
      for (int i = 0; i < 3; ++i) {
        v4f a = {0.f, 0.f, 0.f, 0.f};
#pragma unroll
        for (int k = 0; k < 6; ++k) a = MFMA16(f[i * 6 + k], xr[k], a);
        *reinterpret_cast<v4f*>(ob + (6 + w + 4 * i) * 16) = a;
      }
    } else {
      v8h xr[5];
#pragma unroll
      for (int k = 0; k < 5; ++k) LDAF(10 + k, xr[k]);
#pragma unroll
      for (int i = 0; i < 5; ++i) {
        v4f a = {0.f, 0.f, 0.f, 0.f};
#pragma unroll
        for (int k = 0; k < 5; ++k) a = MFMA16(f[i * 5 + k], xr[k], a);
        *reinterpret_cast<v4f*>(ob + (14 + w + 2 * i) * 16) = a;
      }
    }
  };

#define PIPE(C, SLOT, N)                                        \
  {                                                             \
    asm volatile("s_waitcnt vmcnt(%0)" :: "n"(N) : "memory");   \
    __builtin_amdgcn_s_barrier();                               \
    compute(b + (C) * 256, SLOT);                               \
  }

  // ---- single-barrier ring-5 depth-3 loop (nc = 48 or 49) ----
  stage(b + 3 * 256, 3); PIPE(0, 0, 3 * G)
  stage(b + 4 * 256, 4); PIPE(1, 1, 3 * G + S)
  stage(b + 5 * 256, 0); PIPE(2, 2, 3 * G + 2 * S)
  {
    int ss = 1, sc = 3;                         // slot(c+3)=  (c+3)%5, slot(c)=c%5
    for (int c = 3; c <= nc - 4; ++c) {
      stage(b + (c + 3) * 256, ss); ss = (ss == 4) ? 0 : ss + 1;
      PIPE(c, sc, 3 * G + 3 * S)    sc = (sc == 4) ? 0 : sc + 1;
    }
    PIPE(nc - 3, sc, 2 * G + 3 * S) sc = (sc == 4) ? 0 : sc + 1;
    PIPE(nc - 2, sc, G + 3 * S)     sc = (sc == 4) ? 0 : sc + 1;
    PIPE(nc - 1, sc, 3 * S)
  }
#undef PIPE
#undef LDAF
}

__global__ __launch_bounds__(512, 1) void irrep_linear_k(
    const float* __restrict__ x, const float* __restrict__ W0,
    const float* __restrict__ W1, const float* __restrict__ W2,
    float* __restrict__ out, int n_tiles) {
  __shared__ __align__(16) unsigned char sm[5 * 30720];
  const int t = threadIdx.x;
  const int b = blockIdx.x;
  const int nc = (n_tiles - b + 255) >> 8;    // 48 or 49 grid-stride chunks
  const int w = t >> 6;
  if (w < 2)      wave_main<0, 4>(x, W0, W1, W2, out, sm, t, b, nc);
  else if (w < 6) wave_main<1, 4>(x, W0, W1, W2, out, sm, t, b, nc);
  else            wave_main<2, 3>(x, W0, W1, W2, out, sm, t, b, nc);
}

extern "C" void kernel_launch(void* const* d_in, const int* in_sizes, int n_in,
                              void* d_out, int out_size, void* d_ws, size_t ws_size,
                              hipStream_t stream) {
  const float* x  = (const float*)d_in[0];
  const float* W0 = (const float*)d_in[1];
  const float* W1 = (const float*)d_in[2];
  const float* W2 = (const float*)d_in[3];
  float* out = (float*)d_out;

  const int N = in_sizes[0] / 480;        // 200000
  const int n_tiles = N / 16;             // 12500 tiles of 16 rows
  irrep_linear_k<<<256, 512, 0, stream>>>(x, W0, W1, W2, out, n_tiles);
}

// Round 17
// 152.363 us; speedup vs baseline: 1.2663x; 1.2663x over previous
//
#include <hip/hip_runtime.h>

typedef _Float16 v8h __attribute__((ext_vector_type(8)));
typedef float    v4f __attribute__((ext_vector_type(4)));

#define MFMA16(a, b, c) __builtin_amdgcn_mfma_f32_16x16x32_f16((a), (b), (c), 0, 0, 0)

#define GLL16(gptr, lptr)                                                        \
  __builtin_amdgcn_global_load_lds((const __attribute__((address_space(1))) void*)(gptr), \
                                   (__attribute__((address_space(3))) void*)(lptr), 16, 0, 0)

// Weight-fragment table in d_ws: 154 fragments, layout [frag][lane] of 8 x f16 (16B).
// Non-zero 32(k) x 16(n) tiles of the 480x480 block-diagonal Wbig:
//   ot 0..7   (cols   0..127): kt 0..3   fbase = ot*4
//   ot 8..19  (cols 128..319): kt 4..9   fbase = 32 + (ot-8)*6
//   ot 20..29 (cols 320..479): kt 10..14 fbase = 104 + (ot-20)*5
// Fragment convention (A and B slots identical): lane l, elem e holds
// k = kt*32 + (l>>4)*8 + e; other dim = l&15.
// SWAPPED use: W-frag in A slot, x-frag in B slot -> lane l, reg j =
// out[row l&15][col ot*16 + (l>>4)*4 + j] -> one float4 store per ot.

__global__ void build_frags_k(const float* __restrict__ W0, const float* __restrict__ W1,
                              const float* __restrict__ W2, v8h* __restrict__ frag) {
  const int f = blockIdx.x;
  const int lane = threadIdx.x;
  int ot, kt;
  if (f < 32)       { ot = f >> 2;           kt = f & 3; }
  else if (f < 104) { int q = f - 32;  ot = 8 + q / 6;  kt = 4 + q % 6; }
  else              { int q = f - 104; ot = 20 + q / 5; kt = 10 + q % 5; }
  const int n  = ot * 16 + (lane & 15);
  const int kb = kt * 32 + (lane >> 4) * 8;
  v8h v;
#pragma unroll
  for (int e = 0; e < 8; ++e) {
    const int k = kb + e;
    float wv = 0.0f;
    if (k < 128) {
      if (n < 128) wv = W0[k * 128 + n] * 0.08838834764831845f;           // 1/sqrt(128)
    } else if (k < 320) {
      if (n >= 128 && n < 320) {
        const int i = k - 128, o = n - 128;
        if (i % 3 == o % 3) wv = W1[(i / 3) * 64 + (o / 3)] * 0.125f;     // 1/sqrt(64)
      }
    } else {
      if (n >= 320) {
        const int i = k - 320, o = n - 320;
        if (i % 5 == o % 5) wv = W2[(i / 5) * 32 + (o / 5)] * 0.17677669529663687f; // 1/sqrt(32)
      }
    }
    v[e] = (_Float16)wv;
  }
  frag[f * 64 + lane] = v;
}

// Round-15 verified skeleton (persistent 512-thread blocks 1/CU, 16-row tiles,
// gll staging with source-side bank swizzle, grid-stride assignment, col-block
// wave partition, ONE barrier per tile, frag table from d_ws), with the SINGLE
// isolated change vs round 15: 5-slot ring / depth-3 prefetch (153600B LDS).
//   iter c: stage(c+3) -> vmcnt(N) -> s_barrier -> compute(c)
// Ring safety: compute(c) reads slot c%5 while gll writes land in slots
// (c+1..c+3)%5 (distances 1..3 mod 5); slot c%5 rewritten in window c+2.
// vmcnt (issue order ...gll(c),S(c-3),gll(c+1),S(c-2),gll(c+2),S(c-1),gll(c+3)):
// steady 3G+3S retires exactly gll(c); peels 3G / 3G+S / 3G+2S;
// tails 2G+3S / G+3S / 3S  (nc = 48/49 >= 7).
// Partition: V=0 (w0,1) cb0 kts0-3 ots{w+2i,i<4} S=4; V=1 (w2..5) cb1 kts4-9
// ots{6+w+4i,i<3} S=3; V=2 (w6,7) cb2 kts10-14 ots{14+w+2i,i<5} S=5.
// Staging: 30 x 1024B wave-instructions/tile: waves 0-5 G=4, waves 6-7 G=3.
template <int V, int G>
__device__ __forceinline__ void wave_main(const float* __restrict__ x,
                                          const v8h* __restrict__ frag,
                                          float* __restrict__ out,
                                          unsigned char* sm, int t, int b, int nc) {
  const int lane = t & 63;
  const int w    = t >> 6;
  const int r16  = lane & 15;
  const int g    = lane >> 4;

  constexpr int S  = (V == 0) ? 4 : (V == 1) ? 3 : 5;    // stores per tile
  constexpr int NF = (V == 0) ? 16 : (V == 1) ? 18 : 25; // resident frags

  // ---- persistent B-fragments from the d_ws table (compile-time indices) ----
  v8h f[NF];
  if constexpr (V == 0) {
#pragma unroll
    for (int i = 0; i < 4; ++i)
#pragma unroll
      for (int k = 0; k < 4; ++k)
        f[i * 4 + k] = frag[((w + 2 * i) * 4 + k) * 64 + lane];
  } else if constexpr (V == 1) {
#pragma unroll
    for (int i = 0; i < 3; ++i)
#pragma unroll
      for (int k = 0; k < 6; ++k)
        f[i * 6 + k] = frag[(32 + (w - 2 + 4 * i) * 6 + k) * 64 + lane];
  } else {
#pragma unroll
    for (int i = 0; i < 5; ++i)
#pragma unroll
      for (int k = 0; k < 5; ++k)
        f[i * 5 + k] = frag[(104 + (w - 6 + 2 * i) * 5 + k) * 64 + lane];
  }

  // ---- staging: 16 rows x 1920B = 1920 granules; G gll per wave ----
  auto stage = [&](int tt, int slot) {
    const unsigned char* xt = (const unsigned char*)x + (size_t)tt * 30720u;
    unsigned char* buf = sm + (size_t)slot * 30720u;
#pragma unroll
    for (int i = 0; i < 4; ++i) {
      if (i < 3 || w < 6) {                    // wave-uniform; waves 0..5 do i=3
        const unsigned gl = (unsigned)(i * 512 + t);
        const unsigned r  = gl / 120u;
        const unsigned j  = gl - r * 120u;
        GLL16(xt + r * 1920u + ((j ^ (r & 7u)) << 4), buf + i * 8192 + w * 1024);
      }
    }
  };

#define LDAF(kt, dst)                                                                       \
  {                                                                                         \
    const unsigned j0 = (unsigned)((kt) * 8 + g * 2);                                       \
    const float4 lo = *reinterpret_cast<const float4*>(smc + rb + (((j0) ^ q) << 4));       \
    const float4 hi = *reinterpret_cast<const float4*>(smc + rb + ((((j0) + 1) ^ q) << 4)); \
    v8h v_;                                                                                 \
    v_[0] = (_Float16)lo.x; v_[1] = (_Float16)lo.y;                                         \
    v_[2] = (_Float16)lo.z; v_[3] = (_Float16)lo.w;                                         \
    v_[4] = (_Float16)hi.x; v_[5] = (_Float16)hi.y;                                         \
    v_[6] = (_Float16)hi.z; v_[7] = (_Float16)hi.w;                                         \
    dst = v_;                                                                               \
  }

  auto compute = [&](int tt, int slot) {
    const unsigned char* smc = sm + (size_t)slot * 30720u;
    const unsigned rb = (unsigned)r16 * 1920u;
    const unsigned q  = (unsigned)(r16 & 7u);
    float* const ob = out + ((size_t)tt * 16 + r16) * 480 + g * 4;
    if constexpr (V == 0) {
      v8h xr[4];
#pragma unroll
      for (int k = 0; k < 4; ++k) LDAF(k, xr[k]);
#pragma unroll
      for (int i = 0; i < 4; ++i) {
        v4f a = {0.f, 0.f, 0.f, 0.f};
#pragma unroll
        for (int k = 0; k < 4; ++k) a = MFMA16(f[i * 4 + k], xr[k], a);
        *reinterpret_cast<v4f*>(ob + (w + 2 * i) * 16) = a;
      }
    } else if constexpr (V == 1) {
      v8h xr[6];
#pragma unroll
      for (int k = 0; k < 6; ++k) LDAF(4 + k, xr[k]);
#pragma unroll
      for (int i = 0; i < 3; ++i) {
        v4f a = {0.f, 0.f, 0.f, 0.f};
#pragma unroll
        for (int k = 0; k < 6; ++k) a = MFMA16(f[i * 6 + k], xr[k], a);
        *reinterpret_cast<v4f*>(ob + (6 + w + 4 * i) * 16) = a;
      }
    } else {
      v8h xr[5];
#pragma unroll
      for (int k = 0; k < 5; ++k) LDAF(10 + k, xr[k]);
#pragma unroll
      for (int i = 0; i < 5; ++i) {
        v4f a = {0.f, 0.f, 0.f, 0.f};
#pragma unroll
        for (int k = 0; k < 5; ++k) a = MFMA16(f[i * 5 + k], xr[k], a);
        *reinterpret_cast<v4f*>(ob + (14 + w + 2 * i) * 16) = a;
      }
    }
  };

#define PIPE(C, SLOT, N)                                        \
  {                                                             \
    asm volatile("s_waitcnt vmcnt(%0)" :: "n"(N) : "memory");   \
    __builtin_amdgcn_s_barrier();                               \
    compute(b + (C) * 256, SLOT);                               \
  }

  // ---- single-barrier ring-5 depth-3 loop (nc = 48 or 49) ----
  stage(b, 0);
  stage(b + 256, 1);
  stage(b + 2 * 256, 2);
  stage(b + 3 * 256, 3); PIPE(0, 0, 3 * G)
  stage(b + 4 * 256, 4); PIPE(1, 1, 3 * G + S)
  stage(b + 5 * 256, 0); PIPE(2, 2, 3 * G + 2 * S)
  {
    int ss = 1, sc = 3;                         // slot(c+3)=(c+3)%5, slot(c)=c%5
    for (int c = 3; c <= nc - 4; ++c) {
      stage(b + (c + 3) * 256, ss); ss = (ss == 4) ? 0 : ss + 1;
      PIPE(c, sc, 3 * G + 3 * S)    sc = (sc == 4) ? 0 : sc + 1;
    }
    PIPE(nc - 3, sc, 2 * G + 3 * S) sc = (sc == 4) ? 0 : sc + 1;
    PIPE(nc - 2, sc, G + 3 * S)     sc = (sc == 4) ? 0 : sc + 1;
    PIPE(nc - 1, sc, 3 * S)
  }
#undef PIPE
#undef LDAF
}

__global__ __launch_bounds__(512, 1) void irrep_linear_k(
    const float* __restrict__ x, const v8h* __restrict__ frag, float* __restrict__ out,
    int n_tiles) {
  __shared__ __align__(16) unsigned char sm[5 * 30720];
  const int t = threadIdx.x;
  const int b = blockIdx.x;
  const int nc = (n_tiles - b + 255) >> 8;    // 48 or 49 grid-stride chunks
  const int w = t >> 6;
  if (w < 2)      wave_main<0, 4>(x, frag, out, sm, t, b, nc);
  else if (w < 6) wave_main<1, 4>(x, frag, out, sm, t, b, nc);
  else            wave_main<2, 3>(x, frag, out, sm, t, b, nc);
}

extern "C" void kernel_launch(void* const* d_in, const int* in_sizes, int n_in,
                              void* d_out, int out_size, void* d_ws, size_t ws_size,
                              hipStream_t stream) {
  const float* x  = (const float*)d_in[0];
  const float* W0 = (const float*)d_in[1];
  const float* W1 = (const float*)d_in[2];
  const float* W2 = (const float*)d_in[3];
  float* out = (float*)d_out;
  v8h* frag = (v8h*)d_ws;   // 154 * 64 * 16 B = 157,696 B

  build_frags_k<<<154, 64, 0, stream>>>(W0, W1, W2, frag);

  const int N = in_sizes[0] / 480;        // 200000
  const int n_tiles = N / 16;             // 12500 tiles of 16 rows
  irrep_linear_k<<<256, 512, 0, stream>>>(x, frag, out, n_tiles);
}

// Round 18
// 149.883 us; speedup vs baseline: 1.2872x; 1.0165x over previous
//
#include <hip/hip_runtime.h>

typedef _Float16 v8h __attribute__((ext_vector_type(8)));
typedef float    v4f __attribute__((ext_vector_type(4)));

#define MFMA16(a, b, c) __builtin_amdgcn_mfma_f32_16x16x32_f16((a), (b), (c), 0, 0, 0)

#define GLL16(gptr, lptr)                                                        \
  __builtin_amdgcn_global_load_lds((const __attribute__((address_space(1))) void*)(gptr), \
                                   (__attribute__((address_space(3))) void*)(lptr), 16, 0, 0)

// Weight-fragment table in d_ws: 154 fragments, layout [frag][lane] of 8 x f16 (16B).
// Non-zero 32(k) x 16(n) tiles of the 480x480 block-diagonal Wbig:
//   ot 0..7   (cols   0..127): kt 0..3   fbase = ot*4
//   ot 8..19  (cols 128..319): kt 4..9   fbase = 32 + (ot-8)*6
//   ot 20..29 (cols 320..479): kt 10..14 fbase = 104 + (ot-20)*5
// Fragment convention (A and B slots identical): lane l, elem e holds
// k = kt*32 + (l>>4)*8 + e; other dim = l&15.
// SWAPPED use: W-frag in A slot, x-frag in B slot -> lane l, reg j =
// out[row l&15][col ot*16 + (l>>4)*4 + j] -> one float4 store per ot.

__global__ void build_frags_k(const float* __restrict__ W0, const float* __restrict__ W1,
                              const float* __restrict__ W2, v8h* __restrict__ frag) {
  const int f = blockIdx.x;
  const int lane = threadIdx.x;
  int ot, kt;
  if (f < 32)       { ot = f >> 2;           kt = f & 3; }
  else if (f < 104) { int q = f - 32;  ot = 8 + q / 6;  kt = 4 + q % 6; }
  else              { int q = f - 104; ot = 20 + q / 5; kt = 10 + q % 5; }
  const int n  = ot * 16 + (lane & 15);
  const int kb = kt * 32 + (lane >> 4) * 8;
  v8h v;
#pragma unroll
  for (int e = 0; e < 8; ++e) {
    const int k = kb + e;
    float wv = 0.0f;
    if (k < 128) {
      if (n < 128) wv = W0[k * 128 + n] * 0.08838834764831845f;           // 1/sqrt(128)
    } else if (k < 320) {
      if (n >= 128 && n < 320) {
        const int i = k - 128, o = n - 128;
        if (i % 3 == o % 3) wv = W1[(i / 3) * 64 + (o / 3)] * 0.125f;     // 1/sqrt(64)
      }
    } else {
      if (n >= 320) {
        const int i = k - 320, o = n - 320;
        if (i % 5 == o % 5) wv = W2[(i / 5) * 32 + (o / 5)] * 0.17677669529663687f; // 1/sqrt(32)
      }
    }
    v[e] = (_Float16)wv;
  }
  frag[f * 64 + lane] = v;
}

// Persistent 512-thread blocks, 1/CU. 16-row tiles (30720B) in a 4-slot LDS
// ring, staged 2 ahead via global_load_lds (source-side bank swizzle),
// GRID-STRIDE tile assignment (DRAM row locality), col-block wave partition,
// and ONE barrier per tile:
//   iter c: stage(c+2) -> vmcnt(2G+2S) -> s_barrier -> compute(c)
// Ring safety: between consecutive barriers the concurrent LDS ops are
// compute(c) [slot c&3] and stage(c+3) [slot (c+3)&3] — distance 3 mod 4.
// vmcnt: issue order ...gll(c),S(c-2),gll(c+1),S(c-1),gll(c+2) -> 2G+2S
// retires exactly gll(c); peeled iters 2G / 2G+S / G+2S / 2S.
// Partition: V=0 (w0,1) cb0 kts0-3 ots{w+2i}; V=1 (w2..5) cb1 kts4-9
// ots{6+w+4i}; V=2 (w6,7) cb2 kts10-14 ots{14+w+2i}.
// Staging: 30 x 1024B wave-instructions: waves 0-5 G=4, waves 6-7 G=3.
template <int V, int G>
__device__ __forceinline__ void wave_main(const float* __restrict__ x,
                                          const v8h* __restrict__ frag,
                                          float* __restrict__ out,
                                          unsigned char* sm, int t, int b, int nc) {
  const int lane = t & 63;
  const int w    = t >> 6;
  const int r16  = lane & 15;
  const int g    = lane >> 4;

  constexpr int S  = (V == 0) ? 4 : (V == 1) ? 3 : 5;    // stores per tile
  constexpr int NF = (V == 0) ? 16 : (V == 1) ? 18 : 25; // resident frags

  // ---- persistent B-fragments (compile-time indices) ----
  v8h f[NF];
  if constexpr (V == 0) {
#pragma unroll
    for (int i = 0; i < 4; ++i)
#pragma unroll
      for (int k = 0; k < 4; ++k)
        f[i * 4 + k] = frag[((w + 2 * i) * 4 + k) * 64 + lane];
  } else if constexpr (V == 1) {
#pragma unroll
    for (int i = 0; i < 3; ++i)
#pragma unroll
      for (int k = 0; k < 6; ++k)
        f[i * 6 + k] = frag[(32 + (w - 2 + 4 * i) * 6 + k) * 64 + lane];
  } else {
#pragma unroll
    for (int i = 0; i < 5; ++i)
#pragma unroll
      for (int k = 0; k < 5; ++k)
        f[i * 5 + k] = frag[(104 + (w - 6 + 2 * i) * 5 + k) * 64 + lane];
  }

  // ---- staging: 16 rows x 1920B = 1920 granules; G gll per wave ----
  auto stage = [&](int tt, int slot) {
    const unsigned char* xt = (const unsigned char*)x + (size_t)tt * 30720u;
    unsigned char* buf = sm + (size_t)slot * 30720u;
#pragma unroll
    for (int i = 0; i < 4; ++i) {
      if (i < 3 || w < 6) {                    // wave-uniform; waves 0..5 do i=3
        const unsigned gl = (unsigned)(i * 512 + t);
        const unsigned r  = gl / 120u;
        const unsigned j  = gl - r * 120u;
        GLL16(xt + r * 1920u + ((j ^ (r & 7u)) << 4), buf + i * 8192 + w * 1024);
      }
    }
  };

#define LDAF(kt, dst)                                                                       \
  {                                                                                         \
    const unsigned j0 = (unsigned)((kt) * 8 + g * 2);                                       \
    const float4 lo = *reinterpret_cast<const float4*>(smc + rb + (((j0) ^ q) << 4));       \
    const float4 hi = *reinterpret_cast<const float4*>(smc + rb + ((((j0) + 1) ^ q) << 4)); \
    v8h v_;                                                                                 \
    v_[0] = (_Float16)lo.x; v_[1] = (_Float16)lo.y;                                         \
    v_[2] = (_Float16)lo.z; v_[3] = (_Float16)lo.w;                                         \
    v_[4] = (_Float16)hi.x; v_[5] = (_Float16)hi.y;                                         \
    v_[6] = (_Float16)hi.z; v_[7] = (_Float16)hi.w;                                         \
    dst = v_;                                                                               \
  }

  auto compute = [&](int tt, int slot) {
    const unsigned char* smc = sm + (size_t)slot * 30720u;
    const unsigned rb = (unsigned)r16 * 1920u;
    const unsigned q  = (unsigned)(r16 & 7u);
    float* const ob = out + ((size_t)tt * 16 + r16) * 480 + g * 4;
    if constexpr (V == 0) {
      v8h xr[4];
#pragma unroll
      for (int k = 0; k < 4; ++k) LDAF(k, xr[k]);
#pragma unroll
      for (int i = 0; i < 4; ++i) {
        v4f a = {0.f, 0.f, 0.f, 0.f};
#pragma unroll
        for (int k = 0; k < 4; ++k) a = MFMA16(f[i * 4 + k], xr[k], a);
        *reinterpret_cast<v4f*>(ob + (w + 2 * i) * 16) = a;
      }
    } else if constexpr (V == 1) {
      v8h xr[6];
#pragma unroll
      for (int k = 0; k < 6; ++k) LDAF(4 + k, xr[k]);
#pragma unroll
      for (int i = 0; i < 3; ++i) {
        v4f a = {0.f, 0.f, 0.f, 0.f};
#pragma unroll
        for (int k = 0; k < 6; ++k) a = MFMA16(f[i * 6 + k], xr[k], a);
        *reinterpret_cast<v4f*>(ob + (6 + w + 4 * i) * 16) = a;
      }
    } else {
      v8h xr[5];
#pragma unroll
      for (int k = 0; k < 5; ++k) LDAF(10 + k, xr[k]);
#pragma unroll
      for (int i = 0; i < 5; ++i) {
        v4f a = {0.f, 0.f, 0.f, 0.f};
#pragma unroll
        for (int k = 0; k < 5; ++k) a = MFMA16(f[i * 5 + k], xr[k], a);
        *reinterpret_cast<v4f*>(ob + (14 + w + 2 * i) * 16) = a;
      }
    }
  };

#define PIPE(C, N)                                              \
  {                                                             \
    asm volatile("s_waitcnt vmcnt(%0)" :: "n"(N) : "memory");   \
    __builtin_amdgcn_s_barrier();                               \
    compute(b + (C) * 256, (C) & 3);                            \
  }

  // ---- single-barrier ring-4 loop over grid-stride chunks (nc >= 4) ----
  stage(b, 0);
  stage(b + 256, 1);
  stage(b + 2 * 256, 2); PIPE(0, 2 * G)
  stage(b + 3 * 256, 3); PIPE(1, 2 * G + S)
  for (int c = 2; c <= nc - 3; ++c) {
    stage(b + (c + 2) * 256, (c + 2) & 3);
    PIPE(c, 2 * G + 2 * S)
  }
  PIPE(nc - 2, G + 2 * S)
  PIPE(nc - 1, 2 * S)
#undef PIPE
#undef LDAF
}

__global__ __launch_bounds__(512, 1) void irrep_linear_k(
    const float* __restrict__ x, const v8h* __restrict__ frag, float* __restrict__ out,
    int n_tiles) {
  __shared__ __align__(16) unsigned char sm[4 * 30720];
  const int t = threadIdx.x;
  const int b = blockIdx.x;
  const int nc = (n_tiles - b + 255) >> 8;    // 48 or 49 grid-stride chunks
  const int w = t >> 6;
  if (w < 2)      wave_main<0, 4>(x, frag, out, sm, t, b, nc);
  else if (w < 6) wave_main<1, 4>(x, frag, out, sm, t, b, nc);
  else            wave_main<2, 3>(x, frag, out, sm, t, b, nc);
}

extern "C" void kernel_launch(void* const* d_in, const int* in_sizes, int n_in,
                              void* d_out, int out_size, void* d_ws, size_t ws_size,
                              hipStream_t stream) {
  const float* x  = (const float*)d_in[0];
  const float* W0 = (const float*)d_in[1];
  const float* W1 = (const float*)d_in[2];
  const float* W2 = (const float*)d_in[3];
  float* out = (float*)d_out;
  v8h* frag = (v8h*)d_ws;   // 154 * 64 * 16 B = 157,696 B

  build_frags_k<<<154, 64, 0, stream>>>(W0, W1, W2, frag);

  const int N = in_sizes[0] / 480;        // 200000
  const int n_tiles = N / 16;             // 12500 tiles of 16 rows
  irrep_linear_k<<<256, 512, 0, stream>>>(x, frag, out, n_tiles);
}